// Round 8
// baseline (490.985 us; speedup 1.0000x reference)
//
#include <hip/hip_runtime.h>
#include <hip/hip_cooperative_groups.h>
#include <stdint.h>

namespace cg = cooperative_groups;

// Problem constants (B,C,D,H,W) = (2,1,128,256,256)
#define BB 2
#define DD 128
#define HH 256
#define WW 256
static constexpr int64_t N = (int64_t)BB * DD * HH * WW;   // 16,777,216
static constexpr int WPR    = WW / 64;                     // 4 words per row
static constexpr int NWORDS = BB * DD * HH * WPR;          // 262,144 words (2 MB)
static constexpr int RBLOCKS = 4096;                       // fallback reduce grid

static constexpr int GRID = 1024;                          // 4 blocks/CU on 256 CUs
static constexpr int TPB  = 256;
static constexpr int NWAVES = GRID * (TPB / 64);           // 4096 waves
static constexpr int ROWS = BB * DD * HH;                  // 65,536 W-rows
static constexpr int ROWS_PER_WAVE = ROWS / NWAVES;        // 16

__device__ __forceinline__ uint64_t spread4(uint64_t x) {   // bit i -> bit 4i
    x &= 0xFFFFull;
    x = (x | (x << 24)) & 0x000000FF000000FFull;
    x = (x | (x << 12)) & 0x000F000F000F000Full;
    x = (x | (x << 6))  & 0x0303030303030303ull;
    x = (x | (x << 3))  & 0x1111111111111111ull;
    return x;
}

// ===========================================================================
// Cooperative fused kernel. LDS kept under ~7.1 KB so that 4 blocks/CU fit
// the runtime's cooperative-launch occupancy check (64 KB shared/CU budget):
// phase 2 processes the 4 transposed words one at a time.
// ===========================================================================
__global__ __launch_bounds__(TPB, 4) void fused_all(
    const float* __restrict__ inp, const float* __restrict__ tgt,
    uint64_t* __restrict__ mask0, uint64_t* __restrict__ mask1,
    double* __restrict__ partials, float* __restrict__ out)
{
    cg::grid_group grid = cg::this_grid();
    __shared__ uint64_t raw[22][23];   // +1 pad  (4048 B)
    __shared__ uint64_t yd[22][17];    // +1 pad  (2992 B)
    __shared__ float  wsum[4];
    __shared__ double dsum[4];

    const int tid  = threadIdx.x;
    const int wave = tid >> 6;
    const int lane = tid & 63;
    const int gw   = blockIdx.x * 4 + wave;           // global wave id, 0..4095

    // ---- Phase 1: predicate + X-dilation (transposed bit order) ----
    #pragma unroll
    for (int k = 0; k < ROWS_PER_WAVE; k += 4) {
        float4 t[4];
        #pragma unroll
        for (int u = 0; u < 4; u++) {
            const int row = gw + (k + u) * NWAVES;
            t[u] = ((const float4*)(tgt + (int64_t)row * WW))[lane];
        }
        #pragma unroll
        for (int u = 0; u < 4; u++) {
            const int row = gw + (k + u) * NWAVES;
            const uint64_t W0 = __ballot(t[u].x > 0.0f && t[u].x < 1.0f);
            const uint64_t W1 = __ballot(t[u].y > 0.0f && t[u].y < 1.0f);
            const uint64_t W2 = __ballot(t[u].z > 0.0f && t[u].z < 1.0f);
            const uint64_t W3 = __ballot(t[u].w > 0.0f && t[u].w < 1.0f);
            const uint64_t U  = W0 | W1 | W2 | W3;
            const uint64_t D0 = U | ((W1 | W2 | W3) << 1);
            const uint64_t D1 = U | ((W2 | W3) << 1) | (W0 >> 1);
            const uint64_t D2 = U | (W3 << 1) | ((W0 | W1) >> 1);
            const uint64_t D3 = U | ((W0 | W1 | W2) >> 1);
            uint64_t d = D0;
            if (lane == 1) d = D1;
            if (lane == 2) d = D2;
            if (lane == 3) d = D3;
            if (lane < 4) mask0[(int64_t)row * WPR + lane] = d;
        }
    }
    grid.sync();

    // ---- Phase 2: YZ dilation + transpose fixup (256 tiles, j-looped) ----
    if (blockIdx.x < 256) {
        const int ty = tid & 15, tz = tid >> 4;
        const int y0 = (blockIdx.x & 15) * 16;
        const int z0 = ((blockIdx.x >> 4) & 7) * 16;
        const int b  = blockIdx.x >> 7;

        uint64_t D[4];
        #pragma unroll
        for (int j = 0; j < 4; j++) {
            for (int idx = tid; idx < 22 * 22; idx += TPB) {
                const int zz = idx / 22, yy = idx % 22;
                const int gz = z0 - 3 + zz, gy = y0 - 3 + yy;
                const bool ok = (gz >= 0 && gz < DD && gy >= 0 && gy < HH);
                uint64_t v = 0;
                if (ok) v = mask0[(((int64_t)(b * DD + gz)) * HH + gy) * WPR + j];
                raw[zz][yy] = v;
            }
            __syncthreads();
            for (int idx = tid; idx < 22 * 16; idx += TPB) {
                const int zz = idx >> 4, yy = idx & 15;
                uint64_t v = 0;
                #pragma unroll
                for (int d = 0; d < 7; d++) v |= raw[zz][yy + d];
                yd[zz][yy] = v;
            }
            __syncthreads();
            uint64_t v = 0;
            #pragma unroll
            for (int d = 0; d < 7; d++) v |= yd[tz + d][ty];
            D[j] = v;
            __syncthreads();   // before next j overwrites raw/yd
        }
        // transposed -> linear: word wx bit m = bit(16wx + (m>>2)) of D[m&3]
        uint64_t* o = mask1 + (((int64_t)(b * DD + z0 + tz)) * HH + y0 + ty) * WPR;
        #pragma unroll
        for (int wx = 0; wx < 4; wx++) {
            uint64_t r = 0;
            #pragma unroll
            for (int j = 0; j < 4; j++) r |= spread4(D[j] >> (16 * wx)) << j;
            o[wx] = r;
        }
    }
    grid.sync();

    // ---- Phase 3: weighted L1 partial reduction ----
    static constexpr int64_t GSTRIDE = (int64_t)GRID * TPB;   // 262,144
    static constexpr int KITER = (int)((N / 4) / GSTRIDE);    // 16
    const int64_t gtid = (int64_t)blockIdx.x * TPB + tid;
    float local = 0.0f;
    #pragma unroll 2
    for (int k = 0; k < KITER; k++) {
        const int64_t i = gtid + (int64_t)k * GSTRIDE;
        float4 a = ((const float4*)inp)[i];
        float4 t = ((const float4*)tgt)[i];
        uint64_t w = mask1[i >> 4];
        unsigned nib = (unsigned)(w >> ((i & 15) * 4)) & 0xFu;
        float s;
        s  = fabsf(t.x - a.x) * ((nib & 1u) ? 11.0f : 1.0f);
        s += fabsf(t.y - a.y) * ((nib & 2u) ? 11.0f : 1.0f);
        s += fabsf(t.z - a.z) * ((nib & 4u) ? 11.0f : 1.0f);
        s += fabsf(t.w - a.w) * ((nib & 8u) ? 11.0f : 1.0f);
        local += s;
    }
    #pragma unroll
    for (int off = 32; off > 0; off >>= 1)
        local += __shfl_down(local, off, 64);
    if (lane == 0) wsum[wave] = local;
    __syncthreads();
    if (tid == 0)
        partials[blockIdx.x] = (double)((wsum[0] + wsum[1]) + (wsum[2] + wsum[3]));
    grid.sync();

    // ---- Phase 4: final sum on block 0 ----
    if (blockIdx.x == 0) {
        double loc = 0.0;
        for (int i = tid; i < GRID; i += TPB) loc += partials[i];
        #pragma unroll
        for (int off = 32; off > 0; off >>= 1)
            loc += __shfl_down(loc, off, 64);
        if (lane == 0) dsum[wave] = loc;
        __syncthreads();
        if (tid == 0)
            out[0] = (float)(((dsum[0] + dsum[1]) + (dsum[2] + dsum[3])) / (double)N);
    }
}

// ===========================================================================
// Fallback path: the proven R6 4-kernel pipeline (151.5 us), used only if
// the cooperative launch is rejected by the runtime.
// ===========================================================================
__global__ __launch_bounds__(256) void mask_xdil(const float* __restrict__ tgt,
                                                 uint64_t* __restrict__ mask) {
    const int wave = threadIdx.x >> 6;
    const int lane = threadIdx.x & 63;
    const int row  = blockIdx.x * 4 + wave;
    float4 t = ((const float4*)(tgt + (int64_t)row * WW))[lane];
    const uint64_t W0 = __ballot(t.x > 0.0f && t.x < 1.0f);
    const uint64_t W1 = __ballot(t.y > 0.0f && t.y < 1.0f);
    const uint64_t W2 = __ballot(t.z > 0.0f && t.z < 1.0f);
    const uint64_t W3 = __ballot(t.w > 0.0f && t.w < 1.0f);
    const uint64_t U  = W0 | W1 | W2 | W3;
    const uint64_t D0 = U | ((W1 | W2 | W3) << 1);
    const uint64_t D1 = U | ((W2 | W3) << 1) | (W0 >> 1);
    const uint64_t D2 = U | (W3 << 1) | ((W0 | W1) >> 1);
    const uint64_t D3 = U | ((W0 | W1 | W2) >> 1);
    uint64_t d = D0;
    if (lane == 1) d = D1;
    if (lane == 2) d = D2;
    if (lane == 3) d = D3;
    if (lane < 4) mask[(int64_t)row * WPR + lane] = d;
}

__global__ __launch_bounds__(256) void yz_dil(const uint64_t* __restrict__ in,
                                              uint64_t* __restrict__ out) {
    __shared__ uint64_t raw[4][22][23];
    __shared__ uint64_t yd[4][22][17];
    const int ty = threadIdx.x & 15;
    const int tz = threadIdx.x >> 4;
    const int y0 = blockIdx.x * 16;
    const int z0 = blockIdx.y * 16;
    const int b  = blockIdx.z;
    for (int idx = threadIdx.x; idx < 22 * 22; idx += 256) {
        const int zz = idx / 22, yy = idx % 22;
        const int gz = z0 - 3 + zz, gy = y0 - 3 + yy;
        const bool ok = (gz >= 0 && gz < DD && gy >= 0 && gy < HH);
        const uint64_t* p = in + (((int64_t)(b * DD + gz)) * HH + gy) * WPR;
        #pragma unroll
        for (int j = 0; j < 4; j++) raw[j][zz][yy] = ok ? p[j] : 0ull;
    }
    __syncthreads();
    for (int idx = threadIdx.x; idx < 22 * 16; idx += 256) {
        const int zz = idx >> 4, yy = idx & 15;
        #pragma unroll
        for (int j = 0; j < 4; j++) {
            uint64_t v = 0;
            #pragma unroll
            for (int d = 0; d < 7; d++) v |= raw[j][zz][yy + d];
            yd[j][zz][yy] = v;
        }
    }
    __syncthreads();
    uint64_t D[4];
    #pragma unroll
    for (int j = 0; j < 4; j++) {
        uint64_t v = 0;
        #pragma unroll
        for (int d = 0; d < 7; d++) v |= yd[j][tz + d][ty];
        D[j] = v;
    }
    uint64_t* o = out + (((int64_t)(b * DD + z0 + tz)) * HH + y0 + ty) * WPR;
    #pragma unroll
    for (int wx = 0; wx < 4; wx++) {
        uint64_t r = 0;
        #pragma unroll
        for (int j = 0; j < 4; j++) r |= spread4(D[j] >> (16 * wx)) << j;
        o[wx] = r;
    }
}

__global__ __launch_bounds__(256) void reduce_loss(const float* __restrict__ inp,
                                                   const float* __restrict__ tgt,
                                                   const uint64_t* __restrict__ mask,
                                                   double* __restrict__ partials) {
    const int64_t nvec = N / 4;
    const int64_t stride = (int64_t)RBLOCKS * 256;
    float local = 0.0f;
    for (int64_t i = (int64_t)blockIdx.x * 256 + threadIdx.x; i < nvec; i += stride) {
        float4 a = ((const float4*)inp)[i];
        float4 t = ((const float4*)tgt)[i];
        uint64_t w = mask[i >> 4];
        unsigned nib = (unsigned)(w >> ((i & 15) * 4)) & 0xFu;
        float s;
        s  = fabsf(t.x - a.x) * ((nib & 1u) ? 11.0f : 1.0f);
        s += fabsf(t.y - a.y) * ((nib & 2u) ? 11.0f : 1.0f);
        s += fabsf(t.z - a.z) * ((nib & 4u) ? 11.0f : 1.0f);
        s += fabsf(t.w - a.w) * ((nib & 8u) ? 11.0f : 1.0f);
        local += s;
    }
    #pragma unroll
    for (int off = 32; off > 0; off >>= 1)
        local += __shfl_down(local, off, 64);
    __shared__ float wsum[4];
    const int lane = threadIdx.x & 63;
    const int wv   = threadIdx.x >> 6;
    if (lane == 0) wsum[wv] = local;
    __syncthreads();
    if (threadIdx.x == 0)
        partials[blockIdx.x] = (double)(wsum[0] + wsum[1] + wsum[2] + wsum[3]);
}

__global__ __launch_bounds__(1024) void finalize(const double* __restrict__ partials,
                                                 float* __restrict__ out) {
    double local = 0.0;
    for (int i = threadIdx.x; i < RBLOCKS; i += 1024) local += partials[i];
    #pragma unroll
    for (int off = 32; off > 0; off >>= 1)
        local += __shfl_down(local, off, 64);
    __shared__ double ws[16];
    const int lane = threadIdx.x & 63;
    const int wv   = threadIdx.x >> 6;
    if (lane == 0) ws[wv] = local;
    __syncthreads();
    if (threadIdx.x == 0) {
        double s = 0.0;
        #pragma unroll
        for (int k = 0; k < 16; k++) s += ws[k];
        out[0] = (float)(s / (double)N);
    }
}

extern "C" void kernel_launch(void* const* d_in, const int* in_sizes, int n_in,
                              void* d_out, int out_size, void* d_ws, size_t ws_size,
                              hipStream_t stream) {
    const float* inp = (const float*)d_in[0];   // "input"
    const float* tgt = (const float*)d_in[1];   // "target"
    float* out = (float*)d_out;

    double*   partials = (double*)d_ws;                        // 32 KB (fully written)
    uint64_t* mask0 = (uint64_t*)((char*)d_ws + 64 * 1024);    // 2 MB (transposed)
    uint64_t* mask1 = mask0 + NWORDS;                          // 2 MB (linear)

    void* args[] = {&inp, &tgt, &mask0, &mask1, &partials, &out};
    hipError_t e = hipLaunchCooperativeKernel((const void*)fused_all, dim3(GRID),
                                              dim3(TPB), args, 0, stream);
    if (e != hipSuccess) {
        // Deterministic fallback: proven 4-kernel pipeline (same work).
        mask_xdil<<<16384, 256, 0, stream>>>(tgt, mask0);
        yz_dil<<<dim3(HH / 16, DD / 16, BB), 256, 0, stream>>>(mask0, mask1);
        reduce_loss<<<RBLOCKS, 256, 0, stream>>>(inp, tgt, mask1, partials);
        finalize<<<1, 1024, 0, stream>>>(partials, out);
    }
}

// Round 9
// 321.749 us; speedup vs baseline: 1.5260x; 1.5260x over previous
//
#include <hip/hip_runtime.h>
#include <stdint.h>

// Problem constants (B,C,D,H,W) = (2,1,128,256,256)
#define BB 2
#define DD 128
#define HH 256
#define WW 256
static constexpr int64_t N = (int64_t)BB * DD * HH * WW;   // 16,777,216
static constexpr int WPR    = WW / 64;                     // 4 words per row
static constexpr int NWORDS = BB * DD * HH * WPR;          // 262,144 words (2 MB)
static constexpr int RBLOCKS = 4096;                       // reduce grid

static constexpr int MGRID  = 1024;                        // persistent mask grid
static constexpr int NWAVES = MGRID * 4;                   // 4096 waves
static constexpr int ROWS   = BB * DD * HH;                // 65,536 W-rows
static constexpr int ROWS_PER_WAVE = ROWS / NWAVES;        // 16

__device__ __forceinline__ uint64_t spread4(uint64_t x) {   // bit i -> bit 4i
    x &= 0xFFFFull;
    x = (x | (x << 24)) & 0x000000FF000000FFull;
    x = (x | (x << 12)) & 0x000F000F000F000Full;
    x = (x | (x << 6))  & 0x0303030303030303ull;
    x = (x | (x << 3))  & 0x1111111111111111ull;
    return x;
}

// ---------------------------------------------------------------------------
// K1: predicate + X-dilation, ballot-transposed words, PERSISTENT waves:
// 16 rows/wave in batches of 4 independent float4 loads (4 KB in flight).
// ---------------------------------------------------------------------------
__global__ __launch_bounds__(256) void mask_xdil(const float* __restrict__ tgt,
                                                 uint64_t* __restrict__ mask) {
    const int wave = threadIdx.x >> 6;
    const int lane = threadIdx.x & 63;
    const int gw   = blockIdx.x * 4 + wave;           // global wave id, 0..4095

    #pragma unroll
    for (int k = 0; k < ROWS_PER_WAVE; k += 4) {
        float4 t[4];
        #pragma unroll
        for (int u = 0; u < 4; u++) {
            const int row = gw + (k + u) * NWAVES;
            t[u] = ((const float4*)(tgt + (int64_t)row * WW))[lane];
        }
        #pragma unroll
        for (int u = 0; u < 4; u++) {
            const int row = gw + (k + u) * NWAVES;
            const uint64_t W0 = __ballot(t[u].x > 0.0f && t[u].x < 1.0f);
            const uint64_t W1 = __ballot(t[u].y > 0.0f && t[u].y < 1.0f);
            const uint64_t W2 = __ballot(t[u].z > 0.0f && t[u].z < 1.0f);
            const uint64_t W3 = __ballot(t[u].w > 0.0f && t[u].w < 1.0f);
            const uint64_t U  = W0 | W1 | W2 | W3;
            const uint64_t D0 = U | ((W1 | W2 | W3) << 1);
            const uint64_t D1 = U | ((W2 | W3) << 1) | (W0 >> 1);
            const uint64_t D2 = U | (W3 << 1) | ((W0 | W1) >> 1);
            const uint64_t D3 = U | ((W0 | W1 | W2) >> 1);
            uint64_t d = D0;
            if (lane == 1) d = D1;
            if (lane == 2) d = D2;
            if (lane == 3) d = D3;
            if (lane < 4) mask[(int64_t)row * WPR + lane] = d;
        }
    }
}

// ---------------------------------------------------------------------------
// K2: fused Y+Z dilation (radius 3) on transposed mask, LDS-tiled, with
// transposed->linear bit fixup in the epilogue (R6-proven).
// ---------------------------------------------------------------------------
__global__ __launch_bounds__(256) void yz_dil(const uint64_t* __restrict__ in,
                                              uint64_t* __restrict__ out) {
    __shared__ uint64_t raw[4][22][23];
    __shared__ uint64_t yd[4][22][17];
    const int ty = threadIdx.x & 15;
    const int tz = threadIdx.x >> 4;
    const int y0 = blockIdx.x * 16;
    const int z0 = blockIdx.y * 16;
    const int b  = blockIdx.z;
    for (int idx = threadIdx.x; idx < 22 * 22; idx += 256) {
        const int zz = idx / 22, yy = idx % 22;
        const int gz = z0 - 3 + zz, gy = y0 - 3 + yy;
        const bool ok = (gz >= 0 && gz < DD && gy >= 0 && gy < HH);
        const uint64_t* p = in + (((int64_t)(b * DD + gz)) * HH + gy) * WPR;
        #pragma unroll
        for (int j = 0; j < 4; j++) raw[j][zz][yy] = ok ? p[j] : 0ull;
    }
    __syncthreads();
    for (int idx = threadIdx.x; idx < 22 * 16; idx += 256) {
        const int zz = idx >> 4, yy = idx & 15;
        #pragma unroll
        for (int j = 0; j < 4; j++) {
            uint64_t v = 0;
            #pragma unroll
            for (int d = 0; d < 7; d++) v |= raw[j][zz][yy + d];
            yd[j][zz][yy] = v;
        }
    }
    __syncthreads();
    uint64_t D[4];
    #pragma unroll
    for (int j = 0; j < 4; j++) {
        uint64_t v = 0;
        #pragma unroll
        for (int d = 0; d < 7; d++) v |= yd[j][tz + d][ty];
        D[j] = v;
    }
    uint64_t* o = out + (((int64_t)(b * DD + z0 + tz)) * HH + y0 + ty) * WPR;
    #pragma unroll
    for (int wx = 0; wx < 4; wx++) {
        uint64_t r = 0;
        #pragma unroll
        for (int j = 0; j < 4; j++) r |= spread4(D[j] >> (16 * wx)) << j;
        o[wx] = r;
    }
}

// ---------------------------------------------------------------------------
// K3: weighted L1 reduction with last-block finalize. Per-block partial
// (non-atomic store) -> __threadfence -> atomic ticket; last block sums the
// 4096 partials and writes the mean. Counter zeroed via hipMemsetAsync.
// ---------------------------------------------------------------------------
__global__ __launch_bounds__(256) void reduce_loss(const float* __restrict__ inp,
                                                   const float* __restrict__ tgt,
                                                   const uint64_t* __restrict__ mask,
                                                   double* __restrict__ partials,
                                                   unsigned* __restrict__ count,
                                                   float* __restrict__ out) {
    const int64_t nvec = N / 4;
    const int64_t stride = (int64_t)RBLOCKS * 256;
    float local = 0.0f;
    for (int64_t i = (int64_t)blockIdx.x * 256 + threadIdx.x; i < nvec; i += stride) {
        float4 a = ((const float4*)inp)[i];
        float4 t = ((const float4*)tgt)[i];
        uint64_t w = mask[i >> 4];
        unsigned nib = (unsigned)(w >> ((i & 15) * 4)) & 0xFu;
        float s;
        s  = fabsf(t.x - a.x) * ((nib & 1u) ? 11.0f : 1.0f);
        s += fabsf(t.y - a.y) * ((nib & 2u) ? 11.0f : 1.0f);
        s += fabsf(t.z - a.z) * ((nib & 4u) ? 11.0f : 1.0f);
        s += fabsf(t.w - a.w) * ((nib & 8u) ? 11.0f : 1.0f);
        local += s;
    }
    #pragma unroll
    for (int off = 32; off > 0; off >>= 1)
        local += __shfl_down(local, off, 64);
    __shared__ float wsum[4];
    __shared__ bool last;
    const int lane = threadIdx.x & 63;
    const int wv   = threadIdx.x >> 6;
    if (lane == 0) wsum[wv] = local;
    __syncthreads();
    if (threadIdx.x == 0) {
        partials[blockIdx.x] = (double)((wsum[0] + wsum[1]) + (wsum[2] + wsum[3]));
        __threadfence();                               // partial visible device-wide
        last = (atomicAdd(count, 1u) == RBLOCKS - 1);  // ticket
    }
    __syncthreads();
    if (last) {
        double loc = 0.0;
        for (int i = threadIdx.x; i < RBLOCKS; i += 256) loc += partials[i];
        #pragma unroll
        for (int off = 32; off > 0; off >>= 1)
            loc += __shfl_down(loc, off, 64);
        __shared__ double ds[4];
        if (lane == 0) ds[wv] = loc;
        __syncthreads();
        if (threadIdx.x == 0)
            out[0] = (float)(((ds[0] + ds[1]) + (ds[2] + ds[3])) / (double)N);
    }
}

extern "C" void kernel_launch(void* const* d_in, const int* in_sizes, int n_in,
                              void* d_out, int out_size, void* d_ws, size_t ws_size,
                              hipStream_t stream) {
    const float* inp = (const float*)d_in[0];   // "input"
    const float* tgt = (const float*)d_in[1];   // "target"
    float* out = (float*)d_out;

    double*   partials = (double*)d_ws;                        // 32 KB (fully written)
    unsigned* count = (unsigned*)((char*)d_ws + 40 * 1024);    // 4 B ticket counter
    uint64_t* mask0 = (uint64_t*)((char*)d_ws + 64 * 1024);    // 2 MB (transposed)
    uint64_t* mask1 = mask0 + NWORDS;                          // 2 MB (linear)

    hipMemsetAsync(count, 0, 4, stream);                       // ws is 0xAA-poisoned

    mask_xdil<<<MGRID, 256, 0, stream>>>(tgt, mask0);
    yz_dil<<<dim3(HH / 16, DD / 16, BB), 256, 0, stream>>>(mask0, mask1);
    reduce_loss<<<RBLOCKS, 256, 0, stream>>>(inp, tgt, mask1, partials, count, out);
}